// Round 13
// baseline (143.680 us; speedup 1.0000x reference)
//
#include <hip/hip_runtime.h>
#include <math.h>

// Shapes fixed by setup_inputs(): B=8, N=8192, M=512 clusters, S=64 samples.
#define BB 8
#define NN 8192
#define MM 512
#define SS 64
#define NCLUST (BB*MM)                 // 4096

// d_out layout (flat, return order, all read back as f32):
// new_xyz[8*512*3] | idx(as float)[8*512*64] | attention[8*512] | orientation[8*512]
#define OUT_IDX   (BB*MM*3)            // 12288
#define OUT_ATT   (OUT_IDX + BB*MM*SS) // 274432
#define OUT_ORI   (OUT_ATT + BB*MM)    // 278528

// d_ws layout (ushorts): [0,8192) W2 B-frags | [8192,40960) W3 B-frags.
#define WS_W3 8192

typedef short v8s __attribute__((ext_vector_type(8)));   // 8 bf16 (MFMA A/B frag)
typedef float v4f __attribute__((ext_vector_type(4)));   // MFMA C/D frag

static __device__ __forceinline__ unsigned short f2bf(float x) {
    unsigned int u = __float_as_uint(x);
    u += 0x7FFFu + ((u >> 16) & 1u);     // round-to-nearest-even
    return (unsigned short)(u >> 16);
}

// ---- Kernel 0: pack W2 (64x128) and W3 (128x256) fp32 -> bf16 MFMA B-frag
// layout. B-frag lane l holds B[kt*32+(l>>4)*8+j][nt*16+(l&15)], j=0..7,
// stored contiguous (16 B/lane) so the main kernel loads one dwordx4/frag.
__global__ void pack_weights(const float* __restrict__ W2,
                             const float* __restrict__ W3,
                             unsigned short* __restrict__ ws)
{
    const int gid = blockIdx.x * 256 + threadIdx.x;    // 0..5119
    const float* W; unsigned short* dst; int N, kt, nt, lane;
    if (gid < 1024) {                   // W2: 16 tiles * 64 lanes
        W = W2; N = 128;
        const int tile = gid >> 6; lane = gid & 63;
        kt = tile >> 3; nt = tile & 7;
        dst = ws + (size_t)(tile * 64 + lane) * 8;
    } else {                            // W3: 64 tiles * 64 lanes
        const int g = gid - 1024;
        W = W3; N = 256;
        const int tile = g >> 6; lane = g & 63;
        kt = tile >> 4; nt = tile & 15;
        dst = ws + WS_W3 + (size_t)(tile * 64 + lane) * 8;
    }
    const int k0 = kt * 32 + (lane >> 4) * 8;
    const int n  = nt * 16 + (lane & 15);
    union { unsigned short u[8]; v8s v; } f;
    #pragma unroll
    for (int j = 0; j < 8; ++j) f.u[j] = f2bf(W[(k0 + j) * N + n]);
    *(v8s*)dst = f.v;
}

// ---- Fused kernel, 2 clusters JOINTLY per 512-thread block (straight-line,
// no cluster loop — the sequential-CPB loop was the R4-R6 scratch trigger).
// BQ: waves 0-3 test cluster A, waves 4-7 cluster B, over the SAME point
// range (R10 showed per-stripe search quadruples scan work; R8's joint scan
// typically terminates in 1 iteration). MFMA: M=128 joint. One L4/L5/heads
// pass serves both clusters -> per-cluster barriers/weight-streams halved. ----
__global__ __launch_bounds__(512, 4) void feat3d_fused(
    const float* __restrict__ xyz,
    const float* __restrict__ W1, const float* __restrict__ b1,
    const float* __restrict__ b2, const float* __restrict__ b3,
    const unsigned short* __restrict__ Wp,
    const float* __restrict__ W4, const float* __restrict__ b4,
    const float* __restrict__ W5, const float* __restrict__ b5,
    const float* __restrict__ Wa, const float* __restrict__ ba,
    const float* __restrict__ Wo, const float* __restrict__ bo,
    float* __restrict__ out)
{
    // LDS map (front): [0,16384) a2p [2kt][8mt][64][8] | [16384,49152) a3p
    // [4kt][8mt][64][8]. BQ scratch aliases a3p[0..4224): ls_w1 1K | ls_g 2K |
    // ls_idx 512B | ls_mask 128B — all dead before the L2 epilogue writes a3p.
    // Tail aliases a2p: vbuf[2][256] 2K | h4part[2][8][128] 8K | h4f[2][128]
    // 1K | h5p[2][4][64] 2K.
    __shared__ __align__(16) unsigned char lds[49152];
    unsigned short* a2p = (unsigned short*)lds;
    unsigned short* a3p = (unsigned short*)(lds + 16384);
    float* ls_w1  = (float*)(lds + 16384);                 // [64][4]
    float* ls_g   = (float*)(lds + 17408);                 // [128][4]
    int*   ls_idx = (int*)(lds + 19456);                   // [128]
    unsigned long long* ls_mask = (unsigned long long*)(lds + 19968); // [2][8]

    float* vbuf   = (float*)lds;            // [2][256]
    float* h4part = (float*)(lds + 2048);   // [2][8][128]
    float* h4f    = (float*)(lds + 10240);  // [2][128]
    float* h5p    = (float*)(lds + 11264);  // [2][4][64]

    const int t   = threadIdx.x;
    const int wv  = t >> 6;         // 0..7
    const int l   = t & 63;
    const int q   = l >> 4;
    const int r16 = l & 15;
    const int g   = wv >> 2;        // BQ group = cluster index within pair
    const int wg  = wv & 3;         // wave index within group
    const int blk = blockIdx.x;     // 0..2047
    const int b   = blk >> 8;
    const int m0  = (blk & 255) * 2;
    const float* xb = xyz + (size_t)b * (NN * 3);

    // W2 B-frags: wave wv owns nt=wv (one dwordx4 per kt); in flight through BQ.
    const v8s* W2f = (const v8s*)Wp;
    const v8s bfr0 = W2f[(0*8 + wv)*64 + l];
    const v8s bfr1 = W2f[(1*8 + wv)*64 + l];

    const int mg = m0 + g;          // this thread's BQ cluster
    const float cx = xb[mg*3+0], cy = xb[mg*3+1], cz = xb[mg*3+2];

    if (t < 6) {                    // new_xyz for both clusters
        const int cl = t / 3, d = t - cl*3;
        out[(b*MM + m0 + cl)*3 + d] = xb[(m0 + cl)*3 + d];
    }

    // Stage W1^T + b1 early (overlaps BQ latency).
    if (t < 64) {
        ls_w1[t*4+0] = W1[t];
        ls_w1[t*4+1] = W1[64 + t];
        ls_w1[t*4+2] = W1[128 + t];
        ls_w1[t*4+3] = b1[t];
    }

    // ---- Joint ball query (256 pts/iter per cluster, same j range for both
    // groups -> shared cache lines). First 64 idx with d2 < 4.0 by index;
    // valid lane holds dx,dy,dz so g-vec is written during the scan. ----
    int cntA = 0, cntB = 0;
    {
        int base = 0, pb = 0;
        while (base < NN && (cntA < SS || cntB < SS)) {
            const int myCnt = g ? cntB : cntA;
            int j = 0; float dx = 0.f, dy = 0.f, dz = 0.f; bool valid = false;
            if (myCnt < SS) {                 // wave-uniform skip when done
                j = base + wg*64 + l;
                dx = xb[j*3+0] - cx;
                dy = xb[j*3+1] - cy;
                dz = xb[j*3+2] - cz;
                // no fma contraction: idx must be exact at the d2==4.0 boundary
                const float d2 = __fadd_rn(__fadd_rn(__fmul_rn(dx,dx), __fmul_rn(dy,dy)),
                                           __fmul_rn(dz,dz));
                valid = d2 < 4.0f;
            }
            const unsigned long long mask = __ballot(valid);
            if (l == 0) ls_mask[pb*8 + wv] = mask;
            __syncthreads();
            const unsigned long long k0 = ls_mask[pb*8+0], k1 = ls_mask[pb*8+1],
                                     k2 = ls_mask[pb*8+2], k3 = ls_mask[pb*8+3],
                                     k4 = ls_mask[pb*8+4], k5 = ls_mask[pb*8+5],
                                     k6 = ls_mask[pb*8+6], k7 = ls_mask[pb*8+7];
            int below = __popcll(mask & ((1ull << l) - 1ull));
            if (g == 0) {
                if (wg > 0) below += (int)__popcll(k0);
                if (wg > 1) below += (int)__popcll(k1);
                if (wg > 2) below += (int)__popcll(k2);
            } else {
                if (wg > 0) below += (int)__popcll(k4);
                if (wg > 1) below += (int)__popcll(k5);
                if (wg > 2) below += (int)__popcll(k6);
            }
            const int pos = myCnt + below;
            if (valid && pos < SS) {
                ls_idx[g*64 + pos]        = j;
                ls_g[(g*64 + pos)*4 + 0]  = dx * 0.5f;
                ls_g[(g*64 + pos)*4 + 1]  = dy * 0.5f;
                ls_g[(g*64 + pos)*4 + 2]  = dz * 0.5f;
            }
            cntA += (int)(__popcll(k0) + __popcll(k1) + __popcll(k2) + __popcll(k3));
            if (cntA > SS) cntA = SS;
            cntB += (int)(__popcll(k4) + __popcll(k5) + __popcll(k6) + __popcll(k7));
            if (cntB > SS) cntB = SS;
            base += 256;
            pb ^= 1;               // double-buffered masks
        }
    }
    __syncthreads();
    if (t < 128) {                 // pad with first neighbor (slot 0 per cluster)
        const int cl = t >> 6, s = t & 63;
        const int cnt = cl ? cntB : cntA;
        if (s >= cnt) {
            ls_idx[cl*64 + s]       = ls_idx[cl*64];
            ls_g[(cl*64 + s)*4 + 0] = ls_g[(cl*64)*4 + 0];
            ls_g[(cl*64 + s)*4 + 1] = ls_g[(cl*64)*4 + 1];
            ls_g[(cl*64 + s)*4 + 2] = ls_g[(cl*64)*4 + 2];
        }
    }
    __syncthreads();
    if (t < 128) {
        const int cl = t >> 6, s = t & 63;
        out[OUT_IDX + (b*MM + m0 + cl)*SS + s] = (float)ls_idx[cl*64 + s];
    }

    // ---- L1 (fp32) + pack h1 into A-frag layout (M=128 joint):
    // lane l of wave wv produces sample S = wv*16+r16 (mt=wv), c = kt*32+q*8+j ----
    {
        const int S = wv*16 + r16;
        const float4 g4 = *(const float4*)&ls_g[S*4];
        #pragma unroll
        for (int kt = 0; kt < 2; ++kt) {
            union { unsigned short u[8]; v8s v; } fr;
            #pragma unroll
            for (int j = 0; j < 8; ++j) {
                const int c = kt*32 + q*8 + j;
                const float4 w = *(const float4*)&ls_w1[c*4];
                const float h = fmaf(g4.x, w.x, fmaf(g4.y, w.y, fmaf(g4.z, w.z, w.w)));
                fr.u[j] = f2bf(fmaxf(h, 0.f));
            }
            *(v8s*)&a2p[((kt*8 + wv)*64 + l)*8] = fr.v;
        }
    }
    __syncthreads();

    // ---- L2 MFMA: h2 = relu(h1 @ W2 + b2), M=128. Wave wv owns nt=wv. ----
    {
        const v4f z = {0.f, 0.f, 0.f, 0.f};
        v4f acc[8];
        #pragma unroll
        for (int mt = 0; mt < 8; ++mt) acc[mt] = z;

        #pragma unroll
        for (int mt = 0; mt < 8; ++mt) {
            const v8s a0 = *(const v8s*)&a2p[((0*8 + mt)*64 + l)*8];
            acc[mt] = __builtin_amdgcn_mfma_f32_16x16x32_bf16(a0, bfr0, acc[mt], 0, 0, 0);
            const v8s a1 = *(const v8s*)&a2p[((1*8 + mt)*64 + l)*8];
            acc[mt] = __builtin_amdgcn_mfma_f32_16x16x32_bf16(a1, bfr1, acc[mt], 0, 0, 0);
        }

        // Epilogue: +b2, relu, bf16, scatter into L3 A-frag layout.
        // C/D elem (mt,rg): S = mt*16+q*4+rg, channel c2 = wv*16+r16.
        const int c2  = wv*16 + r16;
        const float bias = b2[c2];
        const int kt3 = c2 >> 5;
        const int lhi = ((c2 >> 3) & 3) << 4;
        const int j3  = c2 & 7;
        #pragma unroll
        for (int mt = 0; mt < 8; ++mt)
            #pragma unroll
            for (int rg = 0; rg < 4; ++rg) {
                const float h = fmaxf(acc[mt][rg] + bias, 0.f);
                const int s15 = q*4 + rg;
                a3p[((kt3*8 + mt)*64 + (lhi | s15))*8 + j3] = f2bf(h);
            }
    }
    __syncthreads();

    // ---- L3 MFMA: wave wv owns mt-half mh=wv>>2 (cluster mh) x nt-quarter
    // nq=wv&3; 2 passes of acc[4][2]; B-frags pipelined one kt ahead.
    // Pool in regs -> vbuf[cluster][256] (fp32). ----
    {
        const v8s* W3f = (const v8s*)(Wp + WS_W3);
        const int mh = wv >> 2;
        const int nq = wv & 3;

        #pragma unroll
        for (int np = 0; np < 2; ++np) {
            const int nt0 = nq*4 + 2*np;
            const v4f z = {0.f, 0.f, 0.f, 0.f};
            v4f acc[4][2];
            #pragma unroll
            for (int mt = 0; mt < 4; ++mt) { acc[mt][0] = z; acc[mt][1] = z; }

            v8s bb0 = W3f[(0*16 + nt0    )*64 + l];
            v8s bb1 = W3f[(0*16 + nt0 + 1)*64 + l];
            #pragma unroll
            for (int kt = 0; kt < 4; ++kt) {
                v8s a[4];
                #pragma unroll
                for (int mt = 0; mt < 4; ++mt)
                    a[mt] = *(const v8s*)&a3p[((kt*8 + mh*4 + mt)*64 + l)*8];
                v8s nb0, nb1;
                if (kt < 3) {
                    nb0 = W3f[((kt+1)*16 + nt0    )*64 + l];
                    nb1 = W3f[((kt+1)*16 + nt0 + 1)*64 + l];
                }
                #pragma unroll
                for (int mt = 0; mt < 4; ++mt) {
                    acc[mt][0] = __builtin_amdgcn_mfma_f32_16x16x32_bf16(
                        a[mt], bb0, acc[mt][0], 0, 0, 0);
                    acc[mt][1] = __builtin_amdgcn_mfma_f32_16x16x32_bf16(
                        a[mt], bb1, acc[mt][1], 0, 0, 0);
                }
                if (kt < 3) { bb0 = nb0; bb1 = nb1; }
            }

            // Pool over the cluster's 64 samples (16 regs + cross-quad shfl);
            // bias+relu after pool (relu monotone, bias per-column commutes).
            #pragma unroll
            for (int ni = 0; ni < 2; ++ni) {
                float mx = acc[0][ni][0];
                #pragma unroll
                for (int mt = 0; mt < 4; ++mt)
                    #pragma unroll
                    for (int rg = 0; rg < 4; ++rg)
                        mx = fmaxf(mx, acc[mt][ni][rg]);
                mx = fmaxf(mx, __shfl_xor(mx, 16));
                mx = fmaxf(mx, __shfl_xor(mx, 32));
                if (q == 0) {
                    const int c = (nt0 + ni)*16 + r16;
                    vbuf[mh*256 + c] = fmaxf(mx + b3[c], 0.f);
                }
            }
        }
    }
    __syncthreads();   // vbuf[2][256] complete; a2p/a3p now dead

    // ---- L4 (fp32), both clusters: h4[cl][c] = b4[c] + sum_k v W4.
    // thread = (cl = t>>8, col-group cgp, k-part kp); W4 read once per block,
    // float4 rows, cache-shared between the two half-blocks. ----
    {
        const int cl  = t >> 8;
        const int tt  = t & 255;
        const int cgp = tt & 31;
        const int kp  = tt >> 5;
        const float4* W4v = (const float4*)W4;                   // [256][32] float4
        const float4* vb4 = (const float4*)&vbuf[cl*256 + kp*32];
        float4 acc = make_float4(0.f, 0.f, 0.f, 0.f);
        #pragma unroll
        for (int kk4 = 0; kk4 < 8; ++kk4) {
            const float4 vv = vb4[kk4];
            const int k = kp*32 + kk4*4;
            const float4 w0 = W4v[(k+0)*32 + cgp];
            const float4 w1 = W4v[(k+1)*32 + cgp];
            const float4 w2 = W4v[(k+2)*32 + cgp];
            const float4 w3 = W4v[(k+3)*32 + cgp];
            acc.x = fmaf(vv.x, w0.x, fmaf(vv.y, w1.x, fmaf(vv.z, w2.x, fmaf(vv.w, w3.x, acc.x))));
            acc.y = fmaf(vv.x, w0.y, fmaf(vv.y, w1.y, fmaf(vv.z, w2.y, fmaf(vv.w, w3.y, acc.y))));
            acc.z = fmaf(vv.x, w0.z, fmaf(vv.y, w1.z, fmaf(vv.z, w2.z, fmaf(vv.w, w3.z, acc.z))));
            acc.w = fmaf(vv.x, w0.w, fmaf(vv.y, w1.w, fmaf(vv.z, w2.w, fmaf(vv.w, w3.w, acc.w))));
        }
        *(float4*)&h4part[((cl*8 + kp)*128) + cgp*4] = acc;
    }
    __syncthreads();
    if (t < 256) {     // reduce 8 k-partials (+b4), both clusters
        const int cl = t >> 7, c = t & 127;
        float s = b4[c];
        #pragma unroll
        for (int kp = 0; kp < 8; ++kp) s += h4part[(cl*8 + kp)*128 + c];
        h4f[cl*128 + c] = s;
    }
    __syncthreads();

    // ---- L5 (fp32): thread = (cl, c5, k-quarter kq). ----
    {
        const int cl = t >> 8;
        const int tt = t & 255;
        const int c5 = tt & 63;
        const int kq = tt >> 6;
        const float* W5c = W5 + c5;
        const float* h4c = h4f + cl*128;
        float acc = 0.f;
        for (int k = kq*32; k < kq*32 + 32; k += 4) {
            const float4 hh = *(const float4*)&h4c[k];
            acc = fmaf(hh.x, W5c[(k+0)*64],
                  fmaf(hh.y, W5c[(k+1)*64],
                  fmaf(hh.z, W5c[(k+2)*64],
                  fmaf(hh.w, W5c[(k+3)*64], acc))));
        }
        h5p[(cl*4 + kq)*64 + c5] = acc;
    }
    __syncthreads();

    // ---- Heads (waves 0-1, one per cluster): attention = softplus(h5.Wa+ba);
    // orientation = atan2(o1,o0) (normalization scale-invariant -> skipped). ----
    if (t < 128) {
        const int cl = t >> 6, ll = t & 63;
        float h5v = b5[ll];
        #pragma unroll
        for (int kq = 0; kq < 4; ++kq) h5v += h5p[(cl*4 + kq)*64 + ll];
        float va = h5v * Wa[ll];
        float v0 = h5v * Wo[2*ll + 0];
        float v1 = h5v * Wo[2*ll + 1];
        #pragma unroll
        for (int off = 32; off > 0; off >>= 1) {
            va += __shfl_down(va, off);
            v0 += __shfl_down(v0, off);
            v1 += __shfl_down(v1, off);
        }
        if (ll == 0) {
            const int cg = b*MM + m0 + cl;
            const float a = va + ba[0];
            out[OUT_ATT + cg] = fmaxf(a, 0.f) + log1pf(expf(-fabsf(a)));
            out[OUT_ORI + cg] = atan2f(v1 + bo[1], v0 + bo[0]);
        }
    }
}

extern "C" void kernel_launch(void* const* d_in, const int* in_sizes, int n_in,
                              void* d_out, int out_size, void* d_ws, size_t ws_size,
                              hipStream_t stream) {
    const float* xyz = (const float*)d_in[0];
    const float* W1  = (const float*)d_in[1];
    const float* b1  = (const float*)d_in[2];
    const float* W2  = (const float*)d_in[3];
    const float* b2  = (const float*)d_in[4];
    const float* W3  = (const float*)d_in[5];
    const float* b3  = (const float*)d_in[6];
    const float* W4  = (const float*)d_in[7];
    const float* b4  = (const float*)d_in[8];
    const float* W5  = (const float*)d_in[9];
    const float* b5  = (const float*)d_in[10];
    const float* Wa  = (const float*)d_in[11];
    const float* ba  = (const float*)d_in[12];
    const float* Wo  = (const float*)d_in[13];
    const float* bo  = (const float*)d_in[14];

    unsigned short* ws = (unsigned short*)d_ws;

    pack_weights<<<dim3(20), dim3(256), 0, stream>>>(W2, W3, ws);
    feat3d_fused<<<dim3(NCLUST/2), dim3(512), 0, stream>>>(
        xyz, W1, b1, b2, b3, ws, W4, b4, W5, b5, Wa, ba, Wo, bo, (float*)d_out);
}

// Round 17
// 134.259 us; speedup vs baseline: 1.0702x; 1.0702x over previous
//
#include <hip/hip_runtime.h>
#include <math.h>

// Shapes fixed by setup_inputs(): B=8, N=8192, M=512 clusters, S=64 samples.
#define BB 8
#define NN 8192
#define MM 512
#define SS 64
#define NCLUST (BB*MM)                 // 4096

// d_out layout (flat, return order, all read back as f32):
// new_xyz[8*512*3] | idx(as float)[8*512*64] | attention[8*512] | orientation[8*512]
#define OUT_IDX   (BB*MM*3)            // 12288
#define OUT_ATT   (OUT_IDX + BB*MM*SS) // 274432
#define OUT_ORI   (OUT_ATT + BB*MM)    // 278528

// d_ws layout (ushorts): [0,8192) W2 B-frags | [8192,40960) W3 B-frags.
#define WS_W3 8192

typedef short v8s __attribute__((ext_vector_type(8)));   // 8 bf16 (MFMA A/B frag)
typedef float v4f __attribute__((ext_vector_type(4)));   // MFMA C/D frag

static __device__ __forceinline__ unsigned short f2bf(float x) {
    unsigned int u = __float_as_uint(x);
    u += 0x7FFFu + ((u >> 16) & 1u);     // round-to-nearest-even
    return (unsigned short)(u >> 16);
}

// ---- Kernel 0: pack W2 (64x128) and W3 (128x256) fp32 -> bf16 MFMA B-frag
// layout. B-frag lane l holds B[kt*32+(l>>4)*8+j][nt*16+(l&15)], j=0..7,
// stored contiguous (16 B/lane) so the main kernel loads one dwordx4/frag.
__global__ void pack_weights(const float* __restrict__ W2,
                             const float* __restrict__ W3,
                             unsigned short* __restrict__ ws)
{
    const int gid = blockIdx.x * 256 + threadIdx.x;    // 0..5119
    const float* W; unsigned short* dst; int N, kt, nt, lane;
    if (gid < 1024) {                   // W2: 16 tiles * 64 lanes
        W = W2; N = 128;
        const int tile = gid >> 6; lane = gid & 63;
        kt = tile >> 3; nt = tile & 7;
        dst = ws + (size_t)(tile * 64 + lane) * 8;
    } else {                            // W3: 64 tiles * 64 lanes
        const int g = gid - 1024;
        W = W3; N = 256;
        const int tile = g >> 6; lane = g & 63;
        kt = tile >> 4; nt = tile & 15;
        dst = ws + WS_W3 + (size_t)(tile * 64 + lane) * 8;
    }
    const int k0 = kt * 32 + (lane >> 4) * 8;
    const int n  = nt * 16 + (lane & 15);
    union { unsigned short u[8]; v8s v; } f;
    #pragma unroll
    for (int j = 0; j < 8; ++j) f.u[j] = f2bf(W[(k0 + j) * N + n]);
    *(v8s*)dst = f.v;
}

// ---- Fused kernel (R8 structure = best measured: 57.2us fused, 132.8 total).
// R14 deltas: (a) pad pass + 1 barrier removed — reads clamp slot to
// (s < cnt ? s : 0); slot 0 IS the TF pad value (globally first valid), and
// cnt>=1 always (the center itself passes d2<4). (b) s_setprio(1) around the
// L2/L3 MFMA clusters — co-resident blocks are phase-skewed by BQ variance,
// so priority arbitration between blocks' waves has room to act (T5). ----
__global__ __launch_bounds__(256, 4) void feat3d_fused(
    const float* __restrict__ xyz,
    const float* __restrict__ W1, const float* __restrict__ b1,
    const float* __restrict__ b2, const float* __restrict__ b3,
    const unsigned short* __restrict__ Wp,
    const float* __restrict__ W4, const float* __restrict__ b4,
    const float* __restrict__ W5, const float* __restrict__ b5,
    const float* __restrict__ Wa, const float* __restrict__ ba,
    const float* __restrict__ Wo, const float* __restrict__ bo,
    float* __restrict__ out)
{
    // LDS map (front): [0,8192) a2p | [8192,24576) a3p.
    //   smallf/ls_idx/ls_mask alias a3p[0..2368): all dead before the L2
    //   epilogue writes a3p (ls_g/ls_w1 last read in L1; ls_idx last read at
    //   the idx store; ls_mask last read in BQ — all before the L1-end sync).
    // LDS map (tail, aliases a2p): vbuf 1K | h4part 4K | h4f 512B | h5p 1K.
    __shared__ __align__(16) unsigned char lds[24576];
    unsigned short* a2p = (unsigned short*)lds;            // h1 A-frags, 8 KB
    unsigned short* a3p = (unsigned short*)(lds + 8192);   // h2 A-frags, 16 KB
    float* smallf       = (float*)(lds + 8192);            // 512 f32: g | w1
    int* ls_idx         = (int*)(lds + 10240);             // 64
    unsigned long long* ls_mask = (unsigned long long*)(lds + 10496); // [2][4]

    float* ls_g  = smallf;         // [64][4]
    float* ls_w1 = smallf + 256;   // [64][4]

    // Epilogue scratch aliases a2p (dead after the L2 MFMA reads, fenced by
    // the pre-L3 __syncthreads):
    float* vbuf   = (float*)lds;            // 256 f32 pooled v (fp32)
    float* h4part = (float*)(lds + 1024);   // [8][128] f32 k-partials
    float* h4f    = (float*)(lds + 5120);   // 128 f32
    float* h5p    = (float*)(lds + 5632);   // [4][64] f32

    const int t   = threadIdx.x;
    const int wv  = t >> 6;
    const int l   = t & 63;
    const int q   = l >> 4;
    const int r16 = l & 15;
    const int blk = blockIdx.x;
    const int b   = blk >> 9;
    const int m   = blk & 511;
    const float* xb = xyz + (size_t)b * (NN * 3);

    // Prefetch W2 B-frags NOW (packed, one dwordx4 each); they stay in flight
    // through the ball query (reg loads aren't drained by __syncthreads).
    const v8s* W2f = (const v8s*)Wp;
    v8s bfr[2][2];
    #pragma unroll
    for (int kt = 0; kt < 2; ++kt)
        #pragma unroll
        for (int ni = 0; ni < 2; ++ni)
            bfr[kt][ni] = W2f[(kt*8 + 2*wv + ni)*64 + l];

    const float cx = xb[m*3+0], cy = xb[m*3+1], cz = xb[m*3+2];

    if (t < 3) out[(b*MM + m)*3 + t] = xb[m*3 + t];   // new_xyz

    // Stage W1^T + b1 early (overlaps BQ latency).
    if (t < 64) {
        ls_w1[t*4+0] = W1[t];
        ls_w1[t*4+1] = W1[64 + t];
        ls_w1[t*4+2] = W1[128 + t];
        ls_w1[t*4+3] = b1[t];
    }

    // ---- Ball query with fused gather (256 pts/iter): first 64 idx with
    // d2 < 4.0 (by index); valid lane already holds dx,dy,dz so g is written
    // during the scan. ----
    int cnt = 0;
    {
        int base = 0, pb = 0;
        while (base < NN && cnt < SS) {
            const int j = base + t;
            const float dx = xb[j*3+0] - cx;
            const float dy = xb[j*3+1] - cy;
            const float dz = xb[j*3+2] - cz;
            // no fma contraction: idx must be exact at the d2==4.0 boundary
            const float d2 = __fadd_rn(__fadd_rn(__fmul_rn(dx,dx), __fmul_rn(dy,dy)),
                                       __fmul_rn(dz,dz));
            const bool valid = d2 < 4.0f;
            const unsigned long long mask = __ballot(valid);
            if (l == 0) ls_mask[pb*4 + wv] = mask;
            __syncthreads();
            const unsigned long long m0 = ls_mask[pb*4+0], m1 = ls_mask[pb*4+1],
                                     m2 = ls_mask[pb*4+2], m3 = ls_mask[pb*4+3];
            int below = __popcll(mask & ((1ull << l) - 1ull));
            if (wv > 0) below += (int)__popcll(m0);
            if (wv > 1) below += (int)__popcll(m1);
            if (wv > 2) below += (int)__popcll(m2);
            const int pos = cnt + below;
            if (valid && pos < SS) {
                ls_idx[pos]   = j;
                ls_g[pos*4+0] = dx * 0.5f;
                ls_g[pos*4+1] = dy * 0.5f;
                ls_g[pos*4+2] = dz * 0.5f;
            }
            cnt += (int)(__popcll(m0) + __popcll(m1) + __popcll(m2) + __popcll(m3));
            if (cnt > SS) cnt = SS;
            base += 256;
            pb ^= 1;               // double-buffered masks
        }
    }
    __syncthreads();   // ls_idx/ls_g[0..cnt) visible; cnt is block-uniform

    // Pad-free: slot select clamps to 0 (= globally first valid = TF pad).
    if (t < 64) out[OUT_IDX + (b*MM + m)*SS + t] = (float)ls_idx[(t < cnt) ? t : 0];

    // ---- L1 (fp32) + pack h1 into A-frag layout:
    // lane l of wave wv produces s = wv*16+r16, c = kt*32+q*8+j ----
    {
        const int s = wv*16 + r16;
        const int sel = (s < cnt) ? s : 0;          // pad via clamped read
        const float4 g4 = *(const float4*)&ls_g[sel*4];
        #pragma unroll
        for (int kt = 0; kt < 2; ++kt) {
            union { unsigned short u[8]; v8s v; } fr;
            #pragma unroll
            for (int j = 0; j < 8; ++j) {
                const int c = kt*32 + q*8 + j;
                const float4 w = *(const float4*)&ls_w1[c*4];
                const float h = fmaf(g4.x, w.x, fmaf(g4.y, w.y, fmaf(g4.z, w.z, w.w)));
                fr.u[j] = f2bf(fmaxf(h, 0.f));
            }
            *(v8s*)&a2p[((kt*4 + wv)*64 + l)*8] = fr.v;
        }
    }
    __syncthreads();

    // ---- L2 MFMA: h2 = relu(h1 @ W2 + b2). Wave wv owns nt {2wv, 2wv+1}. ----
    {
        const v4f z = {0.f, 0.f, 0.f, 0.f};
        v4f acc[4][2];
        #pragma unroll
        for (int mt = 0; mt < 4; ++mt) { acc[mt][0] = z; acc[mt][1] = z; }

        __builtin_amdgcn_s_setprio(1);
        #pragma unroll
        for (int kt = 0; kt < 2; ++kt)
            #pragma unroll
            for (int mt = 0; mt < 4; ++mt) {
                const v8s a = *(const v8s*)&a2p[((kt*4 + mt)*64 + l)*8];
                #pragma unroll
                for (int ni = 0; ni < 2; ++ni)
                    acc[mt][ni] = __builtin_amdgcn_mfma_f32_16x16x32_bf16(
                        a, bfr[kt][ni], acc[mt][ni], 0, 0, 0);
            }
        __builtin_amdgcn_s_setprio(0);

        // Epilogue: +b2, relu, bf16, scatter into L3 A-frag layout.
        // C/D elem (mt,ni,rg): s = mt*16+q*4+rg, c2 = (2wv+ni)*16+r16.
        #pragma unroll
        for (int ni = 0; ni < 2; ++ni) {
            const int c2  = (2*wv + ni)*16 + r16;
            const float bias = b2[c2];
            const int kt3 = c2 >> 5;
            const int lhi = ((c2 >> 3) & 3) << 4;
            const int j3  = c2 & 7;
            #pragma unroll
            for (int mt = 0; mt < 4; ++mt)
                #pragma unroll
                for (int rg = 0; rg < 4; ++rg) {
                    const float h = fmaxf(acc[mt][ni][rg] + bias, 0.f);
                    const int s15 = q*4 + rg;
                    a3p[((kt3*4 + mt)*64 + (lhi | s15))*8 + j3] = f2bf(h);
                }
        }
    }
    __syncthreads();

    // ---- L3 MFMA in 2 passes (acc[4][2] keeps regs <=128).
    // Wave wv owns nt {4wv..4wv+3}; pass np covers nt0=4wv+2np, nt0+1.
    // B-frags software-pipelined one kt ahead. Pool in regs -> vbuf (fp32). ----
    {
        const v8s* W3f = (const v8s*)(Wp + WS_W3);

        #pragma unroll
        for (int np = 0; np < 2; ++np) {
            const int nt0 = 4*wv + 2*np;
            const v4f z = {0.f, 0.f, 0.f, 0.f};
            v4f acc[4][2];
            #pragma unroll
            for (int mt = 0; mt < 4; ++mt) { acc[mt][0] = z; acc[mt][1] = z; }

            v8s bb0 = W3f[(0*16 + nt0    )*64 + l];
            v8s bb1 = W3f[(0*16 + nt0 + 1)*64 + l];
            __builtin_amdgcn_s_setprio(1);
            #pragma unroll
            for (int kt = 0; kt < 4; ++kt) {
                v8s a[4];
                #pragma unroll
                for (int mt = 0; mt < 4; ++mt)
                    a[mt] = *(const v8s*)&a3p[((kt*4 + mt)*64 + l)*8];
                v8s nb0, nb1;
                if (kt < 3) {
                    nb0 = W3f[((kt+1)*16 + nt0    )*64 + l];
                    nb1 = W3f[((kt+1)*16 + nt0 + 1)*64 + l];
                }
                #pragma unroll
                for (int mt = 0; mt < 4; ++mt) {
                    acc[mt][0] = __builtin_amdgcn_mfma_f32_16x16x32_bf16(
                        a[mt], bb0, acc[mt][0], 0, 0, 0);
                    acc[mt][1] = __builtin_amdgcn_mfma_f32_16x16x32_bf16(
                        a[mt], bb1, acc[mt][1], 0, 0, 0);
                }
                if (kt < 3) { bb0 = nb0; bb1 = nb1; }
            }
            __builtin_amdgcn_s_setprio(0);

            // Pool over s (16 regs + cross-quad shfl); bias+relu after pool
            // (relu monotone, bias per-column => commutes). Keep v in fp32 LDS.
            #pragma unroll
            for (int ni = 0; ni < 2; ++ni) {
                float mx = acc[0][ni][0];
                #pragma unroll
                for (int mt = 0; mt < 4; ++mt)
                    #pragma unroll
                    for (int rg = 0; rg < 4; ++rg)
                        mx = fmaxf(mx, acc[mt][ni][rg]);
                mx = fmaxf(mx, __shfl_xor(mx, 16));
                mx = fmaxf(mx, __shfl_xor(mx, 32));
                if (q == 0) {
                    const int c = (nt0 + ni)*16 + r16;
                    vbuf[c] = fmaxf(mx + b3[c], 0.f);
                }
            }
        }
    }
    __syncthreads();   // vbuf[256] complete

    // ---- L4 (fp32): h4[c] = b4[c] + sum_k v[k] W4[k][c].
    // thread = (col-group cgp = t&31 -> 4 cols, k-part kp = t>>5 -> 32 k).
    // float4 row loads (coalesced) + float4 vbuf reads, named acc. ----
    {
        const int cgp = t & 31;
        const int kp  = t >> 5;
        const float4* W4v = (const float4*)W4;           // row-major [256][32] float4
        const float4* vb4 = (const float4*)&vbuf[kp*32]; // this thread's 32-k window
        float4 acc = make_float4(0.f, 0.f, 0.f, 0.f);
        #pragma unroll
        for (int kk4 = 0; kk4 < 8; ++kk4) {
            const float4 vv = vb4[kk4];
            const int k = kp*32 + kk4*4;
            const float4 w0 = W4v[(k+0)*32 + cgp];
            const float4 w1 = W4v[(k+1)*32 + cgp];
            const float4 w2 = W4v[(k+2)*32 + cgp];
            const float4 w3 = W4v[(k+3)*32 + cgp];
            acc.x = fmaf(vv.x, w0.x, fmaf(vv.y, w1.x, fmaf(vv.z, w2.x, fmaf(vv.w, w3.x, acc.x))));
            acc.y = fmaf(vv.x, w0.y, fmaf(vv.y, w1.y, fmaf(vv.z, w2.y, fmaf(vv.w, w3.y, acc.y))));
            acc.z = fmaf(vv.x, w0.z, fmaf(vv.y, w1.z, fmaf(vv.z, w2.z, fmaf(vv.w, w3.z, acc.z))));
            acc.w = fmaf(vv.x, w0.w, fmaf(vv.y, w1.w, fmaf(vv.z, w2.w, fmaf(vv.w, w3.w, acc.w))));
        }
        *(float4*)&h4part[kp*128 + cgp*4] = acc;
    }
    __syncthreads();
    if (t < 128) {     // reduce 8 k-partials (+b4)
        float s = b4[t];
        #pragma unroll
        for (int kp = 0; kp < 8; ++kp) s += h4part[kp*128 + t];
        h4f[t] = s;
    }
    __syncthreads();

    // ---- L5 (fp32): h5[c] = b5[c] + sum_k h4[k] W5[k][c].
    // thread = (c = t&63, k-quarter = t>>6). ----
    {
        const int c5 = t & 63;
        const int kq = t >> 6;
        const float* W5c = W5 + c5;
        float acc = 0.f;
        for (int k = kq*32; k < kq*32 + 32; k += 4) {
            const float4 hh = *(const float4*)&h4f[k];
            acc = fmaf(hh.x, W5c[(k+0)*64],
                  fmaf(hh.y, W5c[(k+1)*64],
                  fmaf(hh.z, W5c[(k+2)*64],
                  fmaf(hh.w, W5c[(k+3)*64], acc))));
        }
        h5p[t] = acc;            // t == kq*64 + c5
    }
    __syncthreads();

    // ---- Heads (wave 0): attention = softplus(h5.Wa+ba);
    // orientation = atan2(o1,o0) (normalization is scale-invariant -> skipped). ----
    if (t < 64) {
        const float h5v = h5p[t] + h5p[64 + t] + h5p[128 + t] + h5p[192 + t] + b5[t];
        float va = h5v * Wa[t];
        float v0 = h5v * Wo[2*t + 0];
        float v1 = h5v * Wo[2*t + 1];
        #pragma unroll
        for (int off = 32; off > 0; off >>= 1) {
            va += __shfl_down(va, off);
            v0 += __shfl_down(v0, off);
            v1 += __shfl_down(v1, off);
        }
        if (t == 0) {
            const float a = va + ba[0];
            out[OUT_ATT + blk] = fmaxf(a, 0.f) + log1pf(expf(-fabsf(a)));
            out[OUT_ORI + blk] = atan2f(v1 + bo[1], v0 + bo[0]);
        }
    }
}

extern "C" void kernel_launch(void* const* d_in, const int* in_sizes, int n_in,
                              void* d_out, int out_size, void* d_ws, size_t ws_size,
                              hipStream_t stream) {
    const float* xyz = (const float*)d_in[0];
    const float* W1  = (const float*)d_in[1];
    const float* b1  = (const float*)d_in[2];
    const float* W2  = (const float*)d_in[3];
    const float* b2  = (const float*)d_in[4];
    const float* W3  = (const float*)d_in[5];
    const float* b3  = (const float*)d_in[6];
    const float* W4  = (const float*)d_in[7];
    const float* b4  = (const float*)d_in[8];
    const float* W5  = (const float*)d_in[9];
    const float* b5  = (const float*)d_in[10];
    const float* Wa  = (const float*)d_in[11];
    const float* ba  = (const float*)d_in[12];
    const float* Wo  = (const float*)d_in[13];
    const float* bo  = (const float*)d_in[14];

    unsigned short* ws = (unsigned short*)d_ws;

    pack_weights<<<dim3(20), dim3(256), 0, stream>>>(W2, W3, ws);
    feat3d_fused<<<dim3(NCLUST), dim3(256), 0, stream>>>(
        xyz, W1, b1, b2, b3, ws, W4, b4, W5, b5, Wa, ba, Wo, bo, (float*)d_out);
}